// Round 7
// baseline (185.542 us; speedup 1.0000x reference)
//
#include <hip/hip_runtime.h>

#define B_     16
#define D_     256
#define HEADS_ 8
#define N_     32
#define H_     56
#define W_     56
#define L_     3136
#define LDA_A  264   // A-tile LDS row stride (shorts): rows 16B-aligned, 2-way banks

typedef short short8 __attribute__((ext_vector_type(8)));
typedef float f32x4  __attribute__((ext_vector_type(4)));

__device__ __forceinline__ unsigned short f2bf(float f) {
    union { float f; unsigned u; } c; c.f = f;
    unsigned u = c.u;
    u += 0x7fffu + ((u >> 16) & 1u);   // RNE
    return (unsigned short)(u >> 16);
}

// ---------------------------------------------------------------------------
// Wv, Wproj fp32 -> bf16; blockIdx.y==2: qtb[b][16][256] bf16 where rows 0..7 =
// q~[b,h,c] = sum_n q[b,hn]*Wk[hn,c], rows 8..15 = 0 (zero-padded MFMA A-operand).
// ---------------------------------------------------------------------------
__global__ __launch_bounds__(256) void convert_w_kernel(
    const float* __restrict__ Wv, const float* __restrict__ Wproj,
    const float* __restrict__ Wk, const float* __restrict__ q,
    unsigned short* __restrict__ Wvb, unsigned short* __restrict__ Wpb,
    unsigned short* __restrict__ qtb)
{
    if (blockIdx.y < 2) {
        const float* src   = (blockIdx.y == 0) ? Wv  : Wproj;
        unsigned short* dst = (blockIdx.y == 0) ? Wvb : Wpb;
        const int i = (blockIdx.x * 256 + threadIdx.x) * 4;
        float4 v = *(const float4*)(src + i);
        uint2 o;
        o.x = (unsigned)f2bf(v.x) | ((unsigned)f2bf(v.y) << 16);
        o.y = (unsigned)f2bf(v.z) | ((unsigned)f2bf(v.w) << 16);
        *(uint2*)(dst + i) = o;
    } else {
        const int b  = blockIdx.x >> 2;
        const int h0 = (blockIdx.x & 3) * 2;
        const int c  = threadIdx.x;
#pragma unroll
        for (int hh = 0; hh < 2; ++hh) {
            const int h = h0 + hh;
            const float* qb = q  + b * D_ + h * N_;
            const float* wr = Wk + (size_t)(h * N_) * D_ + c;
            float acc = 0.f;
#pragma unroll 8
            for (int n = 0; n < N_; ++n)
                acc = fmaf(qb[n], wr[(size_t)n * D_], acc);
            qtb[((size_t)b * 16 + h) * D_ + c]     = f2bf(acc);
            qtb[((size_t)b * 16 + 8 + h) * D_ + c] = 0;
        }
    }
}

// ---------------------------------------------------------------------------
// V = Wv @ x fused with S = q~ @ x.  BM=64 d x BN=64 l per block (blocks never
// straddle batches). One-shot padded A (33KB -> 4 blocks/CU), barrier-free
// K-loop, B gathered from fp32 x with register double-buffer prefetch,
// packed to bf16 via v_cvt_pk_bf16_f32. Extra MFMA row computes S (by==0 only
// stores it). Vo layout [b][h][l][32].
// ---------------------------------------------------------------------------
__global__ __launch_bounds__(256) void gemm_v_mfma(
    const float* __restrict__ x, const unsigned short* __restrict__ Wvb,
    const unsigned short* __restrict__ qtb,
    unsigned short* __restrict__ Vo, float* __restrict__ S)
{
    __shared__ __align__(16) unsigned short As[64 * LDA_A];   // 33 KB

    const int t = threadIdx.x;
    const int w = t >> 6, lane = t & 63, col = lane & 15, quad = lane >> 4;
    const int wr = w >> 1, wc = w & 1;
    const int bb = blockIdx.z;
    const int d0 = blockIdx.y * 64;
    const int l0 = blockIdx.x * 64;
    const bool doS = (blockIdx.y == 0);

    // ---- one-shot A stage: 64 rows x 256 c, pad-264 ----
#pragma unroll
    for (int i = 0; i < 8; ++i) {
        const int u = t + i * 256;
        const int row = u >> 5, cu = (u & 31) * 8;
        *(uint4*)&As[row * LDA_A + cu] =
            *(const uint4*)(Wvb + (size_t)(d0 + row) * D_ + cu);
    }

    // ---- per-lane B/q bases ----
    const float* xg[2];
#pragma unroll
    for (int n = 0; n < 2; ++n)
        xg[n] = x + (size_t)bb * D_ * L_ + (size_t)(quad * 8) * L_
                  + l0 + wc * 32 + n * 16 + col;
    const unsigned short* qg = qtb + ((size_t)bb * 16 + col) * D_ + quad * 8;

    f32x4 acc[2][2], accS[2];
#pragma unroll
    for (int m = 0; m < 2; ++m)
#pragma unroll
        for (int n = 0; n < 2; ++n) acc[m][n] = (f32x4){0.f, 0.f, 0.f, 0.f};
#pragma unroll
    for (int n = 0; n < 2; ++n) accS[n] = (f32x4){0.f, 0.f, 0.f, 0.f};

    // ---- register prefetch buffers (all indices compile-time under unroll) ----
    float pB[2][2][8];
    uint4 pQ[2];
#pragma unroll
    for (int n = 0; n < 2; ++n)
#pragma unroll
        for (int j = 0; j < 8; ++j)
            pB[0][n][j] = xg[n][(size_t)j * L_];
    pQ[0] = *(const uint4*)qg;

    __syncthreads();   // A ready

#pragma unroll
    for (int kt = 0; kt < 8; ++kt) {
        const int cur = kt & 1, nxt = cur ^ 1;
        if (kt < 7) {
#pragma unroll
            for (int n = 0; n < 2; ++n)
#pragma unroll
                for (int j = 0; j < 8; ++j)
                    pB[nxt][n][j] = xg[n][(size_t)((kt + 1) * 32 + j) * L_];
            pQ[nxt] = *(const uint4*)(qg + (kt + 1) * 32);
        }

        short8 bf[2];
#pragma unroll
        for (int n = 0; n < 2; ++n) {
            union { unsigned u[4]; short8 s; } pk;
#pragma unroll
            for (int p = 0; p < 4; ++p)
                asm("v_cvt_pk_bf16_f32 %0, %1, %2" : "=v"(pk.u[p])
                    : "v"(pB[cur][n][2 * p]), "v"(pB[cur][n][2 * p + 1]));
            bf[n] = pk.s;
        }
        short8 af[2];
#pragma unroll
        for (int m = 0; m < 2; ++m)
            af[m] = *(const short8*)&As[(wr * 32 + m * 16 + col) * LDA_A
                                        + kt * 32 + quad * 8];
        const short8 aq = *(const short8*)&pQ[cur];

#pragma unroll
        for (int m = 0; m < 2; ++m)
#pragma unroll
            for (int n = 0; n < 2; ++n)
                acc[m][n] = __builtin_amdgcn_mfma_f32_16x16x32_bf16(
                    af[m], bf[n], acc[m][n], 0, 0, 0);
#pragma unroll
        for (int n = 0; n < 2; ++n)
            accS[n] = __builtin_amdgcn_mfma_f32_16x16x32_bf16(
                aq, bf[n], accS[n], 0, 0, 0);
    }

    // ---- V epilogue: Vo[b][h][l][32], uint2 stores ----
#pragma unroll
    for (int n = 0; n < 2; ++n) {
        const int l = l0 + wc * 32 + n * 16 + col;
#pragma unroll
        for (int m = 0; m < 2; ++m) {
            const int h  = (d0 >> 5) + wr;
            const int dn = m * 16 + quad * 4;
            unsigned short ob[4];
#pragma unroll
            for (int r = 0; r < 4; ++r) ob[r] = f2bf(acc[m][n][r]);
            *(uint2*)(Vo + ((size_t)(bb * HEADS_ + h) * L_ + l) * N_ + dn) =
                *(const uint2*)ob;
        }
    }

    // ---- S epilogue (by==0 only): rows 0..7 of accS are heads ----
    if (doS && quad < 2) {
#pragma unroll
        for (int n = 0; n < 2; ++n) {
            const int l = l0 + wc * 32 + n * 16 + col;
#pragma unroll
            for (int r = 0; r < 4; ++r)
                S[((size_t)bb * HEADS_ + quad * 4 + r) * L_ + l] = accS[n][r];
        }
    }
}

// ---------------------------------------------------------------------------
// attend v4 (verified): block = (8-row band, b*h), all 32 channels.
// V staged as 600 positions x 64B in LDS with XOR chunk swizzle.
// ---------------------------------------------------------------------------
__global__ __launch_bounds__(256) void attend_kernel(
    const float* __restrict__ S, const unsigned short* __restrict__ Vo,
    const float* __restrict__ pos_emb, const float* __restrict__ Wlin,
    unsigned short* __restrict__ Om)
{
    __shared__ __align__(16) unsigned short Vs[600 * 32];  // 37.5 KB swizzled
    __shared__ float Ss[10][58];                           // 2.3 KB

    const int band = blockIdx.x;   // 0..6
    const int bh   = blockIdx.y;   // 0..127
    const int y0   = band * 8;
    const int t    = threadIdx.x;

    const float* Sb = S + (size_t)bh * L_;
    for (int wi = t; wi < 580; wi += 256) {
        const int row = wi / 58, c = wi - row * 58;
        const int gr = y0 - 1 + row, gc = c - 1;
        float v = 0.f;
        if (gr >= 0 && gr < H_ && gc >= 0 && gc < W_)
            v = Sb[gr * W_ + gc];
        Ss[row][c] = v;
    }

    const unsigned short* Vbase = Vo + (size_t)bh * L_ * N_;
    for (int wi = t; wi < 2400; wi += 256) {
        const int p = wi >> 2, i = wi & 3;
        const int row = p / 60, cc = p - row * 60;
        const int gr = y0 - 1 + row, gc = cc - 1;
        uint4 v = make_uint4(0u, 0u, 0u, 0u);
        if (gr >= 0 && gr < H_ && gc >= 0 && gc < W_)
            v = *(const uint4*)(Vbase + (size_t)(gr * W_ + gc) * N_ + i * 8);
        const int sfc = wi ^ (p & 7);          // swizzled 16B-chunk index
        *(uint4*)(Vs + sfc * 8) = v;
    }
    __syncthreads();

    const float scale = Wlin[0] + Wlin[1] + Wlin[2] + Wlin[3];
    const float pe0 = pos_emb[0], pe1 = pos_emb[1], pe2 = pos_emb[2];
    const float pe3 = pos_emb[3], pe4 = pos_emb[4];
    const float bias[9] = {pe0, pe1, pe2, pe1, pe2, pe3, pe2, pe3, pe4};

    for (int idx = t; idx < 448; idx += 256) {
        const int yl = idx / 56, xx = idx - yl * 56;
        const int lr = yl + 1, lc = xx + 1;

        float lg[9], m = -1e30f;
#pragma unroll
        for (int dy = 0; dy < 3; ++dy)
#pragma unroll
            for (int dx = 0; dx < 3; ++dx) {
                const int k = dy * 3 + dx;
                lg[k] = Ss[lr - 1 + dy][lc - 1 + dx] + bias[k];
                m = fmaxf(m, lg[k]);
            }
        float ssum = 0.f;
#pragma unroll
        for (int k = 0; k < 9; ++k) { lg[k] = __expf(lg[k] - m); ssum += lg[k]; }
        const float inv = scale / ssum;

        float om[32];
#pragma unroll
        for (int i = 0; i < 32; ++i) om[i] = 0.f;

#pragma unroll
        for (int dy = 0; dy < 3; ++dy)
#pragma unroll
            for (int dx = 0; dx < 3; ++dx) {
                const float wk = lg[dy * 3 + dx] * inv;
                const int pos  = (lr - 1 + dy) * 60 + (lc - 1 + dx);
                const int base = pos * 4;
                const int msk  = pos & 7;
#pragma unroll
                for (int i = 0; i < 4; ++i) {
                    const int sfc = (base + i) ^ msk;
                    const uint4 v = *(const uint4*)(Vs + sfc * 8);
                    const unsigned* u = (const unsigned*)&v;
#pragma unroll
                    for (int j = 0; j < 4; ++j) {
                        union { unsigned uu; float f; } lo, hi;
                        lo.uu = u[j] << 16;
                        hi.uu = u[j] & 0xffff0000u;
                        om[i * 8 + 2 * j]     = fmaf(wk, lo.f, om[i * 8 + 2 * j]);
                        om[i * 8 + 2 * j + 1] = fmaf(wk, hi.f, om[i * 8 + 2 * j + 1]);
                    }
                }
            }

        unsigned short ob[32];
#pragma unroll
        for (int i = 0; i < 32; ++i) ob[i] = f2bf(om[i]);
        const int l = (y0 + yl) * W_ + xx;
        uint4* dst = (uint4*)(Om + ((size_t)bh * L_ + l) * N_);
        const uint4* sb = (const uint4*)ob;
#pragma unroll
        for (int i = 0; i < 4; ++i) dst[i] = sb[i];
    }
}

// ---------------------------------------------------------------------------
// out = Wproj @ Om.  BM=64 x BN=64, one-shot padded A, barrier-free K-loop
// with register-prefetched B (one dwordx4 per frag: Om K-chunks are heads),
// LDS-staged fp32 epilogue -> 256B-coalesced float4 stores.
// ---------------------------------------------------------------------------
__global__ __launch_bounds__(256) void gemm_proj_mfma(
    const unsigned short* __restrict__ Om, const unsigned short* __restrict__ Wpb,
    float* __restrict__ Out)
{
    __shared__ __align__(16) char smem[64 * LDA_A * 2];     // 33 KB
    unsigned short* As = (unsigned short*)smem;
    float*          Cs = (float*)smem;                      // [64][68] = 17 KB

    const int t = threadIdx.x;
    const int w = t >> 6, lane = t & 63, col = lane & 15, quad = lane >> 4;
    const int wr = w >> 1, wc = w & 1;
    const int bb = blockIdx.z;
    const int d0 = blockIdx.y * 64;
    const int l0 = blockIdx.x * 64;

    // ---- one-shot A stage ----
#pragma unroll
    for (int i = 0; i < 8; ++i) {
        const int u = t + i * 256;
        const int row = u >> 5, cu = (u & 31) * 8;
        *(uint4*)&As[row * LDA_A + cu] =
            *(const uint4*)(Wpb + (size_t)(d0 + row) * D_ + cu);
    }

    // ---- B bases: Om[((bb*8 + kt)*L + l)*32 + quad*8] ----
    const unsigned short* og[2];
#pragma unroll
    for (int n = 0; n < 2; ++n) {
        const int l = l0 + wc * 32 + n * 16 + col;
        og[n] = Om + ((size_t)(bb * HEADS_) * L_ + l) * N_ + quad * 8;
    }
    const size_t kstride = (size_t)L_ * N_;

    f32x4 acc[2][2];
#pragma unroll
    for (int m = 0; m < 2; ++m)
#pragma unroll
        for (int n = 0; n < 2; ++n) acc[m][n] = (f32x4){0.f, 0.f, 0.f, 0.f};

    uint4 pB[2][2];
#pragma unroll
    for (int n = 0; n < 2; ++n) pB[0][n] = *(const uint4*)og[n];

    __syncthreads();   // A ready

#pragma unroll
    for (int kt = 0; kt < 8; ++kt) {
        const int cur = kt & 1, nxt = cur ^ 1;
        if (kt < 7) {
#pragma unroll
            for (int n = 0; n < 2; ++n)
                pB[nxt][n] = *(const uint4*)(og[n] + (size_t)(kt + 1) * kstride);
        }
        short8 af[2];
#pragma unroll
        for (int m = 0; m < 2; ++m)
            af[m] = *(const short8*)&As[(wr * 32 + m * 16 + col) * LDA_A
                                        + kt * 32 + quad * 8];
#pragma unroll
        for (int m = 0; m < 2; ++m)
#pragma unroll
            for (int n = 0; n < 2; ++n)
                acc[m][n] = __builtin_amdgcn_mfma_f32_16x16x32_bf16(
                    af[m], *(const short8*)&pB[cur][n], acc[m][n], 0, 0, 0);
    }

    // ---- LDS-staged epilogue: acc -> Cs[64][68] -> coalesced float4 stores ----
    __syncthreads();   // all waves done reading As
#pragma unroll
    for (int m = 0; m < 2; ++m)
#pragma unroll
        for (int n = 0; n < 2; ++n)
#pragma unroll
            for (int r = 0; r < 4; ++r)
                Cs[(wr * 32 + m * 16 + quad * 4 + r) * 68
                   + wc * 32 + n * 16 + col] = acc[m][n][r];
    __syncthreads();

    float* ob = Out + (size_t)bb * D_ * L_ + (size_t)d0 * L_ + l0;
#pragma unroll
    for (int i = 0; i < 4; ++i) {
        const int u = t + i * 256;
        const int row = u >> 4, lc = (u & 15) * 4;
        *(float4*)(ob + (size_t)row * L_ + lc) = *(const float4*)&Cs[row * 68 + lc];
    }
}

// ---------------------------------------------------------------------------
extern "C" void kernel_launch(void* const* d_in, const int* in_sizes, int n_in,
                              void* d_out, int out_size, void* d_ws, size_t ws_size,
                              hipStream_t stream)
{
    const float* x       = (const float*)d_in[0];
    const float* q       = (const float*)d_in[1];
    const float* Wk      = (const float*)d_in[2];
    const float* Wv      = (const float*)d_in[3];
    const float* pos_emb = (const float*)d_in[4];
    const float* Wlin    = (const float*)d_in[5];
    const float* Wproj   = (const float*)d_in[6];
    float* out = (float*)d_out;

    const size_t planeE = (size_t)B_ * D_ * L_;
    unsigned short* Vo  = (unsigned short*)d_ws;
    unsigned short* Om  = Vo + planeE;
    unsigned short* Wvb = Om + planeE;
    unsigned short* Wpb = Wvb + D_ * D_;
    float*          S   = (float*)(Wpb + D_ * D_);
    unsigned short* qtb = (unsigned short*)(S + (size_t)B_ * HEADS_ * L_);

    convert_w_kernel<<<dim3(64, 3), 256, 0, stream>>>(Wv, Wproj, Wk, q, Wvb, Wpb, qtb);
    gemm_v_mfma<<<dim3(L_ / 64, 4, B_), 256, 0, stream>>>(x, Wvb, qtb, Vo, S);
    attend_kernel<<<dim3(7, B_ * HEADS_), 256, 0, stream>>>(S, Vo, pos_emb, Wlin, Om);
    gemm_proj_mfma<<<dim3(L_ / 64, 4, B_), 256, 0, stream>>>(Om, Wpb, out);
}